// Round 8
// baseline (254.988 us; speedup 1.0000x reference)
//
#include <hip/hip_runtime.h>

// ---------------------------------------------------------------------------
// BlockCrossAttention on MI355X (gfx950).  Round 18 (= r17 resubmitted;
// previous bench died to container failure, not kernel error):
//  - r16 fused the enc fp32->bf16 cast into gemm_qkv but issued the A
//    reg-loads back-to-back with their use (cvt+ds_write) -> full HBM/L2
//    latency exposed per k-tile; gemm_qkv 52us, MfmaUtil 7.4%.
//  - r17/r18 restructures to the flash_attn schedule (T14): A(kt) held in
//    regs across the iteration; prefetch A(kt+1) issued after the post-stage
//    barrier, before the MFMA phase, so it flies under compute; tail
//    barrier is the drain. B gload16 issued at loop top (in flight during
//    cvt+ds_write).
//  - Everything else unchanged from r16.
// ---------------------------------------------------------------------------

typedef unsigned short u16;
typedef __attribute__((ext_vector_type(8))) __bf16 bf16x8;
typedef __attribute__((ext_vector_type(4))) float f32x4;
typedef __attribute__((ext_vector_type(4))) _Float16 f16x4;

static __device__ __forceinline__ u16 f2bf(float f) {        // RNE
    unsigned int u = __float_as_uint(f);
    u = (u + 0x7fffu + ((u >> 16) & 1u)) >> 16;
    return (u16)u;
}
static __device__ __forceinline__ void gload16(const u16* g, u16* l) {
    __builtin_amdgcn_global_load_lds(
        (const __attribute__((address_space(1))) void*)g,
        (__attribute__((address_space(3))) void*)l, 16, 0, 0);
}

// ---------------- all prep in one launch (heavy-first) ---------------------
// [0,1024) pool, [1024,3584) transposes, 3584: mask -> f16 0/1.
__global__ __launch_bounds__(256) void prep_all(const float* __restrict__ hid,
                                                const int* __restrict__ mask,
                                                const float* __restrict__ Wq,
                                                const float* __restrict__ Wk,
                                                const float* __restrict__ Wv,
                                                const float* __restrict__ Wo,
                                                u16* __restrict__ poolb,
                                                u16* __restrict__ mh,
                                                u16* __restrict__ Wq_t,
                                                u16* __restrict__ Wkv_t,
                                                u16* __restrict__ Wo_t) {
    int bid = blockIdx.x;
    if (bid < 1024) {                                  // mean-pool 16 tokens
        const int row = bid;                           // b*512 + n
        const int c4 = threadIdx.x;
        const float4* src = (const float4*)(hid + (size_t)row * 16 * 1024) + c4;
        float4 v[16];
#pragma unroll
        for (int t = 0; t < 16; ++t) v[t] = src[(size_t)t * 256];
#pragma unroll
        for (int t = 0; t < 8; ++t) {
            v[t].x += v[t + 8].x; v[t].y += v[t + 8].y;
            v[t].z += v[t + 8].z; v[t].w += v[t + 8].w;
        }
#pragma unroll
        for (int t = 0; t < 4; ++t) {
            v[t].x += v[t + 4].x; v[t].y += v[t + 4].y;
            v[t].z += v[t + 4].z; v[t].w += v[t + 4].w;
        }
#pragma unroll
        for (int t = 0; t < 2; ++t) {
            v[t].x += v[t + 2].x; v[t].y += v[t + 2].y;
            v[t].z += v[t + 2].z; v[t].w += v[t + 2].w;
        }
        v[0].x += v[1].x; v[0].y += v[1].y; v[0].z += v[1].z; v[0].w += v[1].w;
        ushort4 o;
        o.x = f2bf(v[0].x * 0.0625f); o.y = f2bf(v[0].y * 0.0625f);
        o.z = f2bf(v[0].z * 0.0625f); o.w = f2bf(v[0].w * 0.0625f);
        *(ushort4*)(poolb + (size_t)row * 1024 + c4 * 4) = o;
    } else if (bid < 3584) {                           // weight transpose+cast
        bid -= 1024;
        const float* in; u16* out; int N, nbx, rowoff;
        if (bid < 1024)      { in = Wq; out = Wq_t;  N = 1024; nbx = 32; rowoff = 0; }
        else if (bid < 2048) { in = Wo; out = Wo_t;  N = 1024; nbx = 32; rowoff = 0; bid -= 1024; }
        else if (bid < 2304) { in = Wk; out = Wkv_t; N = 256;  nbx = 8;  rowoff = 0; bid -= 2048; }
        else                 { in = Wv; out = Wkv_t; N = 256;  nbx = 8;  rowoff = 256; bid -= 2304; }
        const int n0 = (bid % nbx) * 32, k0 = (bid / nbx) * 32;
        __shared__ float t[32][33];
        const int tx = threadIdx.x & 31, ty = threadIdx.x >> 5;
#pragma unroll
        for (int i = 0; i < 4; ++i)
            t[ty + 8 * i][tx] = in[(size_t)(k0 + ty + 8 * i) * N + n0 + tx];
        __syncthreads();
#pragma unroll
        for (int i = 0; i < 4; ++i)
            out[(size_t)(rowoff + n0 + ty + 8 * i) * 1024 + k0 + tx] = f2bf(t[tx][ty + 8 * i]);
    } else {                                           // mask -> f16 0/1
#pragma unroll
        for (int k = 0; k < 32; ++k) {
            const int i = threadIdx.x + 256 * k;
            mh[i] = mask[i] ? (u16)0x3C00 : (u16)0;    // f16 1.0 / 0.0
        }
    }
}

// ---------------- 64x64 GEMM core, swizzled LDS ----------------------------
// LDS[row][s] = SRC[row][s ^ (row&7)] (16B slots) via pre-swizzled gload16
// source; fragment reads XOR the slot with (r16&7). 2-way max (free).
template <int MODE>
static __device__ __forceinline__ void gemm_core(const u16* __restrict__ A,
                                                 const u16* __restrict__ Bt,
                                                 u16* __restrict__ outQ,
                                                 float* __restrict__ out_f,
                                                 int m0, int n0, int kt0, int nkt,
                                                 u16* sAB) {
    u16* sA = sAB;
    u16* sB = sAB + 64 * 64;
    const int t = threadIdx.x;
    const int w = t >> 6, lane = t & 63, quad = lane >> 4, r16 = lane & 15;
    const int row8 = lane >> 3, seg = lane & 7;
    const int sseg = ((seg ^ row8) << 3);              // swizzled source col (u16)
    const int rsw = r16 & 7;                           // read-side row swizzle

    f32x4 acc[4];
#pragma unroll
    for (int i = 0; i < 4; ++i) acc[i] = (f32x4){0.f, 0.f, 0.f, 0.f};

    for (int kt = kt0; kt < kt0 + nkt; ++kt) {
        const int k0 = kt * 64;
        __syncthreads();
#pragma unroll
        for (int j = 0; j < 2; ++j) {
            const int ra = w * 16 + j * 8;
            gload16(A + (size_t)(m0 + ra + row8) * 1024 + k0 + sseg, sA + ra * 64);
            gload16(Bt + (size_t)(n0 + ra + row8) * 1024 + k0 + sseg, sB + ra * 64);
        }
        __syncthreads();
#pragma unroll
        for (int kk = 0; kk < 2; ++kk) {
            const int csw = ((kk * 4 + quad) ^ rsw) << 3;
            const bf16x8 af = *(const bf16x8*)(sA + (16 * w + r16) * 64 + csw);
#pragma unroll
            for (int nt = 0; nt < 4; ++nt) {
                const bf16x8 bfv = *(const bf16x8*)(sB + (nt * 16 + r16) * 64 + csw);
                acc[nt] = __builtin_amdgcn_mfma_f32_16x16x32_bf16(af, bfv, acc[nt], 0, 0, 0);
            }
        }
    }

    if (MODE == 0) {
#pragma unroll
        for (int nt = 0; nt < 4; ++nt)
#pragma unroll
            for (int r = 0; r < 4; ++r) {
                const int m = m0 + 16 * w + quad * 4 + r;
                const int c = n0 + nt * 16 + r16;
                const int b = m >> 9, nq = m & 511, g = c >> 8, qh = (c >> 6) & 3, d = c & 63;
                outQ[((((size_t)(b * 4 + g) * 4 + qh) * 512 + nq) << 6) + d] =
                    f2bf(acc[nt][r] * 0.180336880f);   // 0.125*log2(e), exp2 domain
            }
    } else {                                           // MODE 3: plain fp32
#pragma unroll
        for (int nt = 0; nt < 4; ++nt)
#pragma unroll
            for (int r = 0; r < 4; ++r) {
                const int m = m0 + 16 * w + quad * 4 + r;
                const int c = n0 + nt * 16 + r16;
                out_f[(size_t)m * 1024 + c] = acc[nt][r];
            }
    }
}

// ---------------- Q + KV projection in one launch --------------------------
// bx < 512: KV GEMM, 128x64 tile, XCD remap, swizzled LDS. A from enc fp32
// (reg-staged + f2bf + swizzled ds_write, flash-style prefetch pipeline);
// B via gload16.  bx >= 512: Q GEMM, 64x64 tile (gemm_core, poolb bf16).
__global__ __launch_bounds__(256) void gemm_qkv(const u16* __restrict__ poolb,
                                                const float* __restrict__ enc,
                                                const u16* __restrict__ Wq_t,
                                                const u16* __restrict__ Wkv_t,
                                                const int* __restrict__ maskp,
                                                u16* __restrict__ Qa,
                                                u16* __restrict__ Ka,
                                                u16* __restrict__ Va) {
    __shared__ __align__(16) u16 smem[12288];          // 24 KB
    const int bx = blockIdx.x;
    if (bx >= 512) {
        const int b = bx - 512;
        gemm_core<0>(poolb, Wq_t, Qa, nullptr, (b >> 4) * 64, (b & 15) * 64, 0, 16, smem);
        return;
    }
    const int xcd = bx & 7, j = bx >> 3;
    const int mt = xcd * 8 + (j & 7), nt2 = j >> 3;
    const int m0 = mt * 128, n0 = nt2 * 64;
    u16* sA = smem;                                    // 128 x 64
    u16* sB = smem + 128 * 64;                         // 64 x 64
    const int t = threadIdx.x;
    const int w = t >> 6, lane = t & 63, quad = lane >> 4, r16 = lane & 15;
    const int row8 = lane >> 3, seg = lane & 7;
    const int sseg = ((seg ^ row8) << 3);              // swizzled source col (B)
    const int rsw = r16 & 7;

    // A reg-staging: thread t covers row t>>1, 32 contiguous fp32 cols at
    // (t&1)*32; held in av[] across the iteration (flash-style pipeline).
    const int arow = t >> 1, acol0 = (t & 1) * 32;
    const float* Ag0 = enc + (size_t)(m0 + arow) * 1024 + acol0;
    u16* sArow = sA + arow * 64;
    const int aslot0 = acol0 >> 3;                     // 0 or 4
    const int arsw = arow & 7;

    float4 av[8];
    auto ldA = [&](int k0) {
        const float4* Ap = (const float4*)(Ag0 + k0);
#pragma unroll
        for (int q = 0; q < 8; ++q) av[q] = Ap[q];
    };
    auto cvtwriteA = [&]() {
#pragma unroll
        for (int j2 = 0; j2 < 4; ++j2) {
            ushort4 pk[2];
#pragma unroll
            for (int h = 0; h < 2; ++h) {
                const float4 f = av[2 * j2 + h];
                pk[h].x = f2bf(f.x); pk[h].y = f2bf(f.y);
                pk[h].z = f2bf(f.z); pk[h].w = f2bf(f.w);
            }
            u16* dst = sArow + (((aslot0 + j2) ^ arsw) << 3);
            *(ushort4*)dst = pk[0];
            *(ushort4*)(dst + 4) = pk[1];
        }
    };

    f32x4 acc[2][4];
#pragma unroll
    for (int i = 0; i < 2; ++i)
#pragma unroll
        for (int nt = 0; nt < 4; ++nt) acc[i][nt] = (f32x4){0.f, 0.f, 0.f, 0.f};

    ldA(0);                                            // prologue
    for (int kt = 0; kt < 16; ++kt) {
        const int k0 = kt * 64;
        // B async global->LDS: in flight during A cvt+write
#pragma unroll
        for (int p = 0; p < 2; ++p) {
            const int ra = p * 32 + w * 8;
            gload16(Wkv_t + (size_t)(n0 + ra + row8) * 1024 + k0 + sseg, sB + ra * 64);
        }
        cvtwriteA();                                   // consume av (kt)
        __syncthreads();                               // B drained; A visible
        if (kt < 15) ldA(k0 + 64);                     // prefetch kt+1: hides under MFMA
#pragma unroll
        for (int kk = 0; kk < 2; ++kk) {
            const int csw = ((kk * 4 + quad) ^ rsw) << 3;
#pragma unroll
            for (int i = 0; i < 2; ++i) {
                const bf16x8 af = *(const bf16x8*)(sA + (w * 32 + i * 16 + r16) * 64 + csw);
#pragma unroll
                for (int nt = 0; nt < 4; ++nt) {
                    const bf16x8 bfv = *(const bf16x8*)(sB + (nt * 16 + r16) * 64 + csw);
                    acc[i][nt] = __builtin_amdgcn_mfma_f32_16x16x32_bf16(af, bfv, acc[i][nt], 0, 0, 0);
                }
            }
        }
        __syncthreads();                               // frees sA/sB; drains prefetch
    }

    const bool isV = (n0 >= 256);
    const int g = (isV ? (n0 - 256) : n0) >> 6;
    const int b = m0 >> 12, l0 = m0 & 4095;
    if (isV) {
        u16* sT = smem;                                // 64 d x stride 136 (l)
#pragma unroll
        for (int i = 0; i < 2; ++i) {
            float mfl[4];
#pragma unroll
            for (int r = 0; r < 4; ++r)
                mfl[r] = maskp[b * 4096 + l0 + w * 32 + i * 16 + quad * 4 + r] ? 1.f : 0.f;
#pragma unroll
            for (int nt = 0; nt < 4; ++nt)
#pragma unroll
                for (int r = 0; r < 4; ++r) {
                    const int ml = w * 32 + i * 16 + quad * 4 + r, cl = nt * 16 + r16;
                    union { _Float16 h; u16 u; } cv;
                    cv.h = (_Float16)(acc[i][nt][r] * mfl[r]);
                    sT[cl * 136 + ml] = cv.u;
                }
        }
        __syncthreads();
#pragma unroll
        for (int p = 0; p < 4; ++p) {
            const int idx = t + 256 * p, rr = idx >> 4, ch = idx & 15;
            *(int4*)(Va + ((size_t)(b * 4 + g) * 64 + rr) * 4096 + l0 + ch * 8) =
                *(const int4*)(sT + rr * 136 + ch * 8);
        }
    } else {
        u16* sT = smem;                                // 128 l x stride 72 (d)
#pragma unroll
        for (int i = 0; i < 2; ++i)
#pragma unroll
            for (int nt = 0; nt < 4; ++nt)
#pragma unroll
                for (int r = 0; r < 4; ++r) {
                    const int ml = w * 32 + i * 16 + quad * 4 + r, cl = nt * 16 + r16;
                    sT[ml * 72 + cl] = f2bf(acc[i][nt][r]);
                }
        __syncthreads();
#pragma unroll
        for (int p = 0; p < 4; ++p) {
            const int idx = t + 256 * p, rr = idx >> 3, ch = idx & 7;
            *(int4*)(Ka + (((size_t)(b * 4 + g) * 4096 + l0 + rr) << 6) + ch * 8) =
                *(const int4*)(sT + rr * 72 + ch * 8);
        }
    }
}

// ---------------- fused attn @ Wo + x16 broadcast --------------------------
// Swizzled LDS; nontemporal output stores (f32x4 ext-vector).
__global__ __launch_bounds__(256) void gemm_o_bcast(const u16* __restrict__ attn,
                                                    const u16* __restrict__ Wo_t,
                                                    float* __restrict__ out) {
    __shared__ __align__(16) u16 smem[2][8192];        // dbuf A|B, 32 KB
    __shared__ __align__(16) float sf[64 * 68];        // fp32 tile, stride 68
    const int bx = blockIdx.x;
    const int m0 = (bx >> 4) * 64, n0 = (bx & 15) * 64;
    const int t = threadIdx.x;
    const int w = t >> 6, lane = t & 63, quad = lane >> 4, r16 = lane & 15;
    const int row8 = lane >> 3, seg = lane & 7;
    const int sseg = ((seg ^ row8) << 3);
    const int rsw = r16 & 7;

    f32x4 acc[4];
#pragma unroll
    for (int i = 0; i < 4; ++i) acc[i] = (f32x4){0.f, 0.f, 0.f, 0.f};

    auto stage = [&](int kt, int bi) {
        const int k0 = kt * 64;
        u16* sA = smem[bi];
        u16* sB = smem[bi] + 4096;
#pragma unroll
        for (int j = 0; j < 2; ++j) {
            const int ra = w * 16 + j * 8;
            gload16(attn + (size_t)(m0 + ra + row8) * 1024 + k0 + sseg, sA + ra * 64);
            gload16(Wo_t + (size_t)(n0 + ra + row8) * 1024 + k0 + sseg, sB + ra * 64);
        }
    };
    stage(0, 0);
    for (int kt = 0; kt < 16; ++kt) {
        const int bi = kt & 1;
        __syncthreads();                               // drains stage(kt)
        if (kt < 15) stage(kt + 1, bi ^ 1);            // issue next-tile loads
        const u16* sA = smem[bi];
        const u16* sB = smem[bi] + 4096;
#pragma unroll
        for (int kk = 0; kk < 2; ++kk) {
            const int csw = ((kk * 4 + quad) ^ rsw) << 3;
            const bf16x8 af = *(const bf16x8*)(sA + (16 * w + r16) * 64 + csw);
#pragma unroll
            for (int nt = 0; nt < 4; ++nt) {
                const bf16x8 bfv = *(const bf16x8*)(sB + (nt * 16 + r16) * 64 + csw);
                acc[nt] = __builtin_amdgcn_mfma_f32_16x16x32_bf16(af, bfv, acc[nt], 0, 0, 0);
            }
        }
    }
    __syncthreads();
#pragma unroll
    for (int nt = 0; nt < 4; ++nt)
#pragma unroll
        for (int r = 0; r < 4; ++r)
            sf[(16 * w + quad * 4 + r) * 68 + nt * 16 + r16] = acc[nt][r];
    __syncthreads();
    const int rr = t >> 4, ch = t & 15;                // 16 rows, 16 f4/row
#pragma unroll
    for (int i = 0; i < 4; ++i) {
        const int row = i * 16 + rr;
        const int m = m0 + row, b = m >> 9, n = m & 511;
        const f32x4 v = *(const f32x4*)(sf + row * 68 + ch * 4);
        f32x4* dst = (f32x4*)(out + ((size_t)b * 8192 + (size_t)n * 16) * 1024 + n0) + ch;
#pragma unroll
        for (int rep = 0; rep < 16; ++rep)
            __builtin_nontemporal_store(v, dst + (size_t)rep * 256);   // 16 token rows
    }
}

// ---------------- flash attention: 1024 thr, block-local split-4 -----------
// (unchanged from r13 — already swizzled)
__global__ __launch_bounds__(1024, 4) void flash_attn(const u16* __restrict__ Qa,
                                                      const u16* __restrict__ Ka,
                                                      const u16* __restrict__ Vt,
                                                      const u16* __restrict__ mh,
                                                      u16* __restrict__ attnout) {
    const int bx = blockIdx.x;
    const int gb = bx & 7, s16 = bx >> 3;            // XCD-aware
    const int g = gb & 3, b = gb >> 2;
    __shared__ __align__(16) u16 sKV[4][2][4096];    // 64 KB
    const int t = threadIdx.x;
    const int wv = t >> 6, grp = wv >> 2, qh = wv & 3;
    const int lane = t & 63, quad = lane >> 4, r16 = lane & 15;

    u16* sK = sKV[grp][0];
    u16* sV = sKV[grp][1];

    bf16x8 aq[2];
    {
        const size_t qbase = ((((size_t)gb * 4 + qh) * 512) + s16 * 16 + r16) * 64;
#pragma unroll
        for (int kk = 0; kk < 2; ++kk)
            aq[kk] = *(const bf16x8*)(Qa + qbase + kk * 32 + quad * 8);
    }
    const u16* Kg = Ka + (size_t)gb * 4096 * 64;     // [l][d] bf16
    const u16* Vg = Vt + (size_t)gb * 64 * 4096;     // [d][l] f16 (masked)
    const u16* mb = mh + b * 4096 + quad * 4;

    const int tg = t & 255;
    const int r0 = tg >> 3, ks = tg & 7, r1 = r0 + 32;
    const int off0 = (r0 * 64 + ks * 8) ^ ((r0 & 7) << 3);   // XOR-swizzled
    const int off1 = (r1 * 64 + ks * 8) ^ ((r1 & 7) << 3);

    f32x4 o[4], lacc;
#pragma unroll
    for (int i = 0; i < 4; ++i) o[i] = (f32x4){0.f, 0.f, 0.f, 0.f};
    lacc = (f32x4){0.f, 0.f, 0.f, 0.f};

    int4 rk0, rk1, rv0, rv1;
    auto ldtile = [&](int l0) {
        rk0 = *(const int4*)(Kg + (size_t)(l0 + r0) * 64 + ks * 8);
        rk1 = *(const int4*)(Kg + (size_t)(l0 + r1) * 64 + ks * 8);
        rv0 = *(const int4*)(Vg + (size_t)r0 * 4096 + l0 + ks * 8);
        rv1 = *(const int4*)(Vg + (size_t)r1 * 4096 + l0 + ks * 8);
    };
    auto sttile = [&]() {
        *(int4*)(sK + off0) = rk0;
        *(int4*)(sK + off1) = rk1;
        *(int4*)(sV + off0) = rv0;
        *(int4*)(sV + off1) = rv1;
    };

    ldtile(grp * 64);
    for (int i = 0; i < 16; ++i) {
        const int l0 = (i * 4 + grp) * 64;
        sttile();
        __syncthreads();                             // group writes visible
        if (i < 15) ldtile(l0 + 256);                // T14: hide under compute

        f32x4 st[4];
#pragma unroll
        for (int nt = 0; nt < 4; ++nt) st[nt] = (f32x4){0.f, 0.f, 0.f, 0.f};
#pragma unroll
        for (int kk = 0; kk < 2; ++kk)
#pragma unroll
            for (int nt = 0; nt < 4; ++nt) {
                const int kidx = ((nt * 16 + r16) * 64 + kk * 32 + quad * 8) ^ ((r16 & 7) << 3);
                const bf16x8 ka = *(const bf16x8*)(sK + kidx);
                st[nt] = __builtin_amdgcn_mfma_f32_16x16x32_bf16(ka, aq[kk], st[nt], 0, 0, 0);
            }

#pragma unroll
        for (int nt = 0; nt < 4; ++nt) {
            f16x4 pa;
#pragma unroll
            for (int j = 0; j < 4; ++j)
                pa[j] = (_Float16)__builtin_amdgcn_exp2f(st[nt][j]);
            const f16x4 bvm = *(const f16x4*)(mb + l0 + nt * 16);
            lacc = __builtin_amdgcn_mfma_f32_16x16x16f16(pa, bvm, lacc, 0, 0, 0);
#pragma unroll
            for (int dt = 0; dt < 4; ++dt) {
                const int vidx = ((dt * 16 + r16) * 64 + nt * 16 + quad * 4) ^ ((r16 & 7) << 3);
                const f16x4 bv = *(const f16x4*)(sV + vidx);
                o[dt] = __builtin_amdgcn_mfma_f32_16x16x16f16(pa, bv, o[dt], 0, 0, 0);
            }
        }
        __syncthreads();                             // reads done, buffer free
    }

    // ---- block-local combine: groups 1-3 dump partials, group 0 sums ------
    float* fp = (float*)sKV;                         // 16384 floats
    if (grp > 0) {
#pragma unroll
        for (int dt = 0; dt < 4; ++dt)
#pragma unroll
            for (int r = 0; r < 4; ++r)
                fp[(grp - 1) * 4096 + qh * 1024 + (quad * 4 + r) * 64 + dt * 16 + r16] = o[dt][r];
        if (r16 == 0) {
#pragma unroll
            for (int r = 0; r < 4; ++r)
                fp[12288 + ((grp - 1) * 4 + qh) * 16 + quad * 4 + r] = lacc[r];
        }
    }
    __syncthreads();
    if (grp == 0) {
        float Ls[4];
#pragma unroll
        for (int r = 0; r < 4; ++r) Ls[r] = lacc[r];
#pragma unroll
        for (int p = 0; p < 3; ++p) {
#pragma unroll
            for (int dt = 0; dt < 4; ++dt)
#pragma unroll
                for (int r = 0; r < 4; ++r)
                    o[dt][r] += fp[p * 4096 + qh * 1024 + (quad * 4 + r) * 64 + dt * 16 + r16];
#pragma unroll
            for (int r = 0; r < 4; ++r)
                Ls[r] += fp[12288 + (p * 4 + qh) * 16 + quad * 4 + r];
        }
        const size_t obase = ((size_t)b * 512 + s16 * 16) * 1024 + (g * 4 + qh) * 64;
#pragma unroll
        for (int r = 0; r < 4; ++r) {
            const float invL = 1.f / Ls[r];
            const size_t rbase = obase + (size_t)(quad * 4 + r) * 1024;
#pragma unroll
            for (int dt = 0; dt < 4; ++dt)
                attnout[rbase + dt * 16 + r16] = f2bf(o[dt][r] * invL);
        }
    }
}

// ---------------------------------------------------------------------------
extern "C" void kernel_launch(void* const* d_in, const int* in_sizes, int n_in,
                              void* d_out, int out_size, void* d_ws, size_t ws_size,
                              hipStream_t stream) {
    const float* hid  = (const float*)d_in[0];
    const float* enc  = (const float*)d_in[1];
    const int*   mask = (const int*)d_in[2];
    const float* Wq   = (const float*)d_in[3];
    const float* Wk   = (const float*)d_in[4];
    const float* Wv   = (const float*)d_in[5];
    const float* Wo   = (const float*)d_in[6];
    float* out = (float*)d_out;

    char* ws = (char*)d_ws;
    size_t off = 0;
    auto alloc = [&](size_t bytes) -> char* {
        char* p = ws + off;
        off += (bytes + 255) & ~(size_t)255;
        return p;
    };
    u16* Wq_t  = (u16*)alloc((size_t)1024 * 1024 * 2);
    u16* Wkv_t = (u16*)alloc((size_t)512 * 1024 * 2);
    u16* Wo_t  = (u16*)alloc((size_t)1024 * 1024 * 2);
    u16* poolb = (u16*)alloc((size_t)1024 * 1024 * 2);     // 2 MB
    u16* Qa    = (u16*)alloc((size_t)1024 * 1024 * 2);
    u16* Ka    = (u16*)alloc((size_t)8 * 4096 * 64 * 2);   // bf16 [l][d]
    u16* Va    = (u16*)alloc((size_t)8 * 4096 * 64 * 2);   // f16  [d][l], masked
    u16* attn  = (u16*)alloc((size_t)1024 * 1024 * 2);
    u16* mh    = (u16*)alloc((size_t)8192 * 2);            // f16 0/1 mask

    prep_all<<<3585, 256, 0, stream>>>(hid, mask, Wq, Wk, Wv, Wo,
                                       poolb, mh, Wq_t, Wkv_t, Wo_t);
    gemm_qkv<<<768, 256, 0, stream>>>(poolb, enc, Wq_t, Wkv_t, mask, Qa, Ka, Va);
    flash_attn<<<256, 1024, 0, stream>>>(Qa, Ka, Va, mh, attn);
    gemm_o_bcast<<<256, 256, 0, stream>>>(attn, Wo_t, out);
}

// Round 9
// 219.951 us; speedup vs baseline: 1.1593x; 1.1593x over previous
//
#include <hip/hip_runtime.h>

// ---------------------------------------------------------------------------
// BlockCrossAttention on MI355X (gfx950).  Round 19 (= r15 revert + o_bcast
// retile):
//  - r16-r18 enc-cast fusion REVERTED: reg-staged A in gemm_qkv lost 32us at
//    26% occupancy vs the gload16 path (52-58us vs ~20us); prep's 17us
//    saving never paid for it. Back to r15's known-good 229.3us structure.
//  - gemm_o_bcast: 64x64 tiles/grid 256 (1 block/CU, 12.5% occupancy — same
//    disease as r12's flash) -> 32x32 tiles/grid 1024 (4 blocks/CU, 50%).
//    A/B panels are 2MB each (L2/L3-resident), so extra re-reads are free.
//    Epilogue via 32x36 fp32 LDS tile -> coalesced nontemporal stores.
//  - prep_all / gemm_qkv / flash_attn byte-identical to r15.
// ---------------------------------------------------------------------------

typedef unsigned short u16;
typedef __attribute__((ext_vector_type(8))) __bf16 bf16x8;
typedef __attribute__((ext_vector_type(4))) float f32x4;
typedef __attribute__((ext_vector_type(4))) _Float16 f16x4;

static __device__ __forceinline__ u16 f2bf(float f) {        // RNE
    unsigned int u = __float_as_uint(f);
    u = (u + 0x7fffu + ((u >> 16) & 1u)) >> 16;
    return (u16)u;
}
static __device__ __forceinline__ void gload16(const u16* g, u16* l) {
    __builtin_amdgcn_global_load_lds(
        (const __attribute__((address_space(1))) void*)g,
        (__attribute__((address_space(3))) void*)l, 16, 0, 0);
}

// ---------------- all prep in one launch (heavy-first) ---------------------
__global__ __launch_bounds__(256) void prep_all(const float* __restrict__ enc,
                                                const float* __restrict__ hid,
                                                const int* __restrict__ mask,
                                                const float* __restrict__ Wq,
                                                const float* __restrict__ Wk,
                                                const float* __restrict__ Wv,
                                                const float* __restrict__ Wo,
                                                u16* __restrict__ encb,
                                                u16* __restrict__ poolb,
                                                u16* __restrict__ mh,
                                                u16* __restrict__ Wq_t,
                                                u16* __restrict__ Wkv_t,
                                                u16* __restrict__ Wo_t) {
    int bid = blockIdx.x;
    if (bid < 1024) {                                  // mean-pool 16 tokens
        const int row = bid;                           // b*512 + n
        const int c4 = threadIdx.x;
        const float4* src = (const float4*)(hid + (size_t)row * 16 * 1024) + c4;
        float4 v[16];
#pragma unroll
        for (int t = 0; t < 16; ++t) v[t] = src[(size_t)t * 256];
#pragma unroll
        for (int t = 0; t < 8; ++t) {
            v[t].x += v[t + 8].x; v[t].y += v[t + 8].y;
            v[t].z += v[t + 8].z; v[t].w += v[t + 8].w;
        }
#pragma unroll
        for (int t = 0; t < 4; ++t) {
            v[t].x += v[t + 4].x; v[t].y += v[t + 4].y;
            v[t].z += v[t + 4].z; v[t].w += v[t + 4].w;
        }
#pragma unroll
        for (int t = 0; t < 2; ++t) {
            v[t].x += v[t + 2].x; v[t].y += v[t + 2].y;
            v[t].z += v[t + 2].z; v[t].w += v[t + 2].w;
        }
        v[0].x += v[1].x; v[0].y += v[1].y; v[0].z += v[1].z; v[0].w += v[1].w;
        ushort4 o;
        o.x = f2bf(v[0].x * 0.0625f); o.y = f2bf(v[0].y * 0.0625f);
        o.z = f2bf(v[0].z * 0.0625f); o.w = f2bf(v[0].w * 0.0625f);
        *(ushort4*)(poolb + (size_t)row * 1024 + c4 * 4) = o;
    } else if (bid < 2048) {                           // enc fp32->bf16, x8 ILP
        const int base = (bid - 1024) * 2048 + threadIdx.x;
        float4 v[8];
#pragma unroll
        for (int j = 0; j < 8; ++j) v[j] = ((const float4*)enc)[base + j * 256];
#pragma unroll
        for (int j = 0; j < 8; ++j) {
            ushort4 o;
            o.x = f2bf(v[j].x); o.y = f2bf(v[j].y);
            o.z = f2bf(v[j].z); o.w = f2bf(v[j].w);
            ((ushort4*)encb)[base + j * 256] = o;
        }
    } else if (bid < 4608) {                           // weight transpose+cast
        bid -= 2048;
        const float* in; u16* out; int N, nbx, rowoff;
        if (bid < 1024)      { in = Wq; out = Wq_t;  N = 1024; nbx = 32; rowoff = 0; }
        else if (bid < 2048) { in = Wo; out = Wo_t;  N = 1024; nbx = 32; rowoff = 0; bid -= 1024; }
        else if (bid < 2304) { in = Wk; out = Wkv_t; N = 256;  nbx = 8;  rowoff = 0; bid -= 2048; }
        else                 { in = Wv; out = Wkv_t; N = 256;  nbx = 8;  rowoff = 256; bid -= 2304; }
        const int n0 = (bid % nbx) * 32, k0 = (bid / nbx) * 32;
        __shared__ float t[32][33];
        const int tx = threadIdx.x & 31, ty = threadIdx.x >> 5;
#pragma unroll
        for (int i = 0; i < 4; ++i)
            t[ty + 8 * i][tx] = in[(size_t)(k0 + ty + 8 * i) * N + n0 + tx];
        __syncthreads();
#pragma unroll
        for (int i = 0; i < 4; ++i)
            out[(size_t)(rowoff + n0 + ty + 8 * i) * 1024 + k0 + tx] = f2bf(t[tx][ty + 8 * i]);
    } else {                                           // mask -> f16 0/1
#pragma unroll
        for (int k = 0; k < 32; ++k) {
            const int i = threadIdx.x + 256 * k;
            mh[i] = mask[i] ? (u16)0x3C00 : (u16)0;    // f16 1.0 / 0.0
        }
    }
}

// ---------------- 64x64 GEMM core, swizzled LDS ----------------------------
// LDS[row][s] = SRC[row][s ^ (row&7)] (16B slots) via pre-swizzled gload16
// source; fragment reads XOR the slot with (r16&7). 2-way max (free).
template <int MODE>
static __device__ __forceinline__ void gemm_core(const u16* __restrict__ A,
                                                 const u16* __restrict__ Bt,
                                                 u16* __restrict__ outQ,
                                                 float* __restrict__ out_f,
                                                 int m0, int n0, int kt0, int nkt,
                                                 u16* sAB) {
    u16* sA = sAB;
    u16* sB = sAB + 64 * 64;
    const int t = threadIdx.x;
    const int w = t >> 6, lane = t & 63, quad = lane >> 4, r16 = lane & 15;
    const int row8 = lane >> 3, seg = lane & 7;
    const int sseg = ((seg ^ row8) << 3);              // swizzled source col (u16)
    const int rsw = r16 & 7;                           // read-side row swizzle

    f32x4 acc[4];
#pragma unroll
    for (int i = 0; i < 4; ++i) acc[i] = (f32x4){0.f, 0.f, 0.f, 0.f};

    for (int kt = kt0; kt < kt0 + nkt; ++kt) {
        const int k0 = kt * 64;
        __syncthreads();
#pragma unroll
        for (int j = 0; j < 2; ++j) {
            const int ra = w * 16 + j * 8;
            gload16(A + (size_t)(m0 + ra + row8) * 1024 + k0 + sseg, sA + ra * 64);
            gload16(Bt + (size_t)(n0 + ra + row8) * 1024 + k0 + sseg, sB + ra * 64);
        }
        __syncthreads();
#pragma unroll
        for (int kk = 0; kk < 2; ++kk) {
            const int csw = ((kk * 4 + quad) ^ rsw) << 3;
            const bf16x8 af = *(const bf16x8*)(sA + (16 * w + r16) * 64 + csw);
#pragma unroll
            for (int nt = 0; nt < 4; ++nt) {
                const bf16x8 bfv = *(const bf16x8*)(sB + (nt * 16 + r16) * 64 + csw);
                acc[nt] = __builtin_amdgcn_mfma_f32_16x16x32_bf16(af, bfv, acc[nt], 0, 0, 0);
            }
        }
    }

    if (MODE == 0) {
#pragma unroll
        for (int nt = 0; nt < 4; ++nt)
#pragma unroll
            for (int r = 0; r < 4; ++r) {
                const int m = m0 + 16 * w + quad * 4 + r;
                const int c = n0 + nt * 16 + r16;
                const int b = m >> 9, nq = m & 511, g = c >> 8, qh = (c >> 6) & 3, d = c & 63;
                outQ[((((size_t)(b * 4 + g) * 4 + qh) * 512 + nq) << 6) + d] =
                    f2bf(acc[nt][r] * 0.180336880f);   // 0.125*log2(e), exp2 domain
            }
    } else {                                           // MODE 3: plain fp32
#pragma unroll
        for (int nt = 0; nt < 4; ++nt)
#pragma unroll
            for (int r = 0; r < 4; ++r) {
                const int m = m0 + 16 * w + quad * 4 + r;
                const int c = n0 + nt * 16 + r16;
                out_f[(size_t)m * 1024 + c] = acc[nt][r];
            }
    }
}

// ---------------- Q + KV projection in one launch --------------------------
// bx < 512: KV GEMM, 128x64 tile, XCD remap, swizzled LDS.
// bx >= 512: Q GEMM, 64x64 tile (gemm_core).
__global__ __launch_bounds__(256) void gemm_qkv(const u16* __restrict__ poolb,
                                                const u16* __restrict__ encb,
                                                const u16* __restrict__ Wq_t,
                                                const u16* __restrict__ Wkv_t,
                                                const int* __restrict__ maskp,
                                                u16* __restrict__ Qa,
                                                u16* __restrict__ Ka,
                                                u16* __restrict__ Va) {
    __shared__ __align__(16) u16 smem[12288];          // 24 KB
    const int bx = blockIdx.x;
    if (bx >= 512) {
        const int b = bx - 512;
        gemm_core<0>(poolb, Wq_t, Qa, nullptr, (b >> 4) * 64, (b & 15) * 64, 0, 16, smem);
        return;
    }
    const int xcd = bx & 7, j = bx >> 3;
    const int mt = xcd * 8 + (j & 7), nt2 = j >> 3;
    const int m0 = mt * 128, n0 = nt2 * 64;
    u16* sA = smem;                                    // 128 x 64
    u16* sB = smem + 128 * 64;                         // 64 x 64
    const int t = threadIdx.x;
    const int w = t >> 6, lane = t & 63, quad = lane >> 4, r16 = lane & 15;
    const int row8 = lane >> 3, seg = lane & 7;
    const int sseg = ((seg ^ row8) << 3);              // swizzled source col
    const int rsw = r16 & 7;

    f32x4 acc[2][4];
#pragma unroll
    for (int i = 0; i < 2; ++i)
#pragma unroll
        for (int nt = 0; nt < 4; ++nt) acc[i][nt] = (f32x4){0.f, 0.f, 0.f, 0.f};

    for (int kt = 0; kt < 16; ++kt) {
        const int k0 = kt * 64;
        __syncthreads();
#pragma unroll
        for (int p = 0; p < 4; ++p) {
            const int ra = p * 32 + w * 8;
            gload16(encb + (size_t)(m0 + ra + row8) * 1024 + k0 + sseg, sA + ra * 64);
        }
#pragma unroll
        for (int p = 0; p < 2; ++p) {
            const int ra = p * 32 + w * 8;
            gload16(Wkv_t + (size_t)(n0 + ra + row8) * 1024 + k0 + sseg, sB + ra * 64);
        }
        __syncthreads();
#pragma unroll
        for (int kk = 0; kk < 2; ++kk) {
            const int csw = ((kk * 4 + quad) ^ rsw) << 3;
#pragma unroll
            for (int i = 0; i < 2; ++i) {
                const bf16x8 af = *(const bf16x8*)(sA + (w * 32 + i * 16 + r16) * 64 + csw);
#pragma unroll
                for (int nt = 0; nt < 4; ++nt) {
                    const bf16x8 bfv = *(const bf16x8*)(sB + (nt * 16 + r16) * 64 + csw);
                    acc[i][nt] = __builtin_amdgcn_mfma_f32_16x16x32_bf16(af, bfv, acc[i][nt], 0, 0, 0);
                }
            }
        }
    }

    const bool isV = (n0 >= 256);
    const int g = (isV ? (n0 - 256) : n0) >> 6;
    const int b = m0 >> 12, l0 = m0 & 4095;
    __syncthreads();
    if (isV) {
        u16* sT = smem;                                // 64 d x stride 136 (l)
#pragma unroll
        for (int i = 0; i < 2; ++i) {
            float mfl[4];
#pragma unroll
            for (int r = 0; r < 4; ++r)
                mfl[r] = maskp[b * 4096 + l0 + w * 32 + i * 16 + quad * 4 + r] ? 1.f : 0.f;
#pragma unroll
            for (int nt = 0; nt < 4; ++nt)
#pragma unroll
                for (int r = 0; r < 4; ++r) {
                    const int ml = w * 32 + i * 16 + quad * 4 + r, cl = nt * 16 + r16;
                    union { _Float16 h; u16 u; } cv;
                    cv.h = (_Float16)(acc[i][nt][r] * mfl[r]);
                    sT[cl * 136 + ml] = cv.u;
                }
        }
        __syncthreads();
#pragma unroll
        for (int p = 0; p < 4; ++p) {
            const int idx = t + 256 * p, rr = idx >> 4, ch = idx & 15;
            *(int4*)(Va + ((size_t)(b * 4 + g) * 64 + rr) * 4096 + l0 + ch * 8) =
                *(const int4*)(sT + rr * 136 + ch * 8);
        }
    } else {
        u16* sT = smem;                                // 128 l x stride 72 (d)
#pragma unroll
        for (int i = 0; i < 2; ++i)
#pragma unroll
            for (int nt = 0; nt < 4; ++nt)
#pragma unroll
                for (int r = 0; r < 4; ++r) {
                    const int ml = w * 32 + i * 16 + quad * 4 + r, cl = nt * 16 + r16;
                    sT[ml * 72 + cl] = f2bf(acc[i][nt][r]);
                }
        __syncthreads();
#pragma unroll
        for (int p = 0; p < 4; ++p) {
            const int idx = t + 256 * p, rr = idx >> 3, ch = idx & 7;
            *(int4*)(Ka + (((size_t)(b * 4 + g) * 4096 + l0 + rr) << 6) + ch * 8) =
                *(const int4*)(sT + rr * 72 + ch * 8);
        }
    }
}

// ---------------- fused attn @ Wo + x16 broadcast, 32x32 tiles -------------
// grid 1024 (32 m-tiles x 32 n-tiles) -> 4 blocks/CU, 50% occupancy (was
// 256 blocks = 1/CU = 12.5%). A(2MB)/B(2MB) are L2/L3-resident, extra
// re-reads free. Each wave owns one 16x16 quadrant. Swizzled LDS staging,
// dbuf; epilogue via 32x36 fp32 LDS tile -> nontemporal f32x4 stores x16.
__global__ __launch_bounds__(256) void gemm_o_bcast(const u16* __restrict__ attn,
                                                    const u16* __restrict__ Wo_t,
                                                    float* __restrict__ out) {
    __shared__ __align__(16) u16 smem[2][4096];        // dbuf: A 32x64 | B 32x64
    const int bx = blockIdx.x;
    const int m0 = (bx >> 5) * 32, n0 = (bx & 31) * 32;
    const int t = threadIdx.x;
    const int w = t >> 6, lane = t & 63, quad = lane >> 4, r16 = lane & 15;
    const int row8 = lane >> 3, seg = lane & 7;
    const int sseg = ((seg ^ row8) << 3);              // swizzled source col
    const int rsw = r16 & 7;
    const int wr = w >> 1, wc = w & 1;                 // quadrant of 32x32

    f32x4 acc = (f32x4){0.f, 0.f, 0.f, 0.f};

    auto stage = [&](int kt, int bi) {
        const int k0 = kt * 64;
        u16* sA = smem[bi];
        u16* sB = smem[bi] + 2048;
        gload16(attn + (size_t)(m0 + w * 8 + row8) * 1024 + k0 + sseg, sA + w * 8 * 64);
        gload16(Wo_t + (size_t)(n0 + w * 8 + row8) * 1024 + k0 + sseg, sB + w * 8 * 64);
    };
    stage(0, 0);
    for (int kt = 0; kt < 16; ++kt) {
        const int bi = kt & 1;
        __syncthreads();                               // drains stage(kt)
        if (kt < 15) stage(kt + 1, bi ^ 1);            // next tile in flight
        const u16* sA = smem[bi];
        const u16* sB = smem[bi] + 2048;
#pragma unroll
        for (int kk = 0; kk < 2; ++kk) {
            const int csw = ((kk * 4 + quad) ^ rsw) << 3;
            const bf16x8 af = *(const bf16x8*)(sA + (wr * 16 + r16) * 64 + csw);
            const bf16x8 bfv = *(const bf16x8*)(sB + (wc * 16 + r16) * 64 + csw);
            acc = __builtin_amdgcn_mfma_f32_16x16x32_bf16(af, bfv, acc, 0, 0, 0);
        }
    }
    __syncthreads();
    float* sf = (float*)smem;                          // 32 x 36 fp32 tile
#pragma unroll
    for (int r = 0; r < 4; ++r)
        sf[(wr * 16 + quad * 4 + r) * 36 + wc * 16 + r16] = acc[r];
    __syncthreads();
    const int row = t >> 3, ch = t & 7;                // 32 rows x 8 f32x4
    const f32x4 v = *(const f32x4*)(sf + row * 36 + ch * 4);
    const int m = m0 + row, b = m >> 9, n = m & 511;
    f32x4* dst = (f32x4*)(out + ((size_t)b * 8192 + (size_t)n * 16) * 1024 + n0) + ch;
#pragma unroll
    for (int rep = 0; rep < 16; ++rep)
        __builtin_nontemporal_store(v, dst + (size_t)rep * 256);   // 16 token rows
}

// ---------------- flash attention: 1024 thr, block-local split-4 -----------
// (unchanged from r13/r15)
__global__ __launch_bounds__(1024, 4) void flash_attn(const u16* __restrict__ Qa,
                                                      const u16* __restrict__ Ka,
                                                      const u16* __restrict__ Vt,
                                                      const u16* __restrict__ mh,
                                                      u16* __restrict__ attnout) {
    const int bx = blockIdx.x;
    const int gb = bx & 7, s16 = bx >> 3;            // XCD-aware
    const int g = gb & 3, b = gb >> 2;
    __shared__ __align__(16) u16 sKV[4][2][4096];    // 64 KB
    const int t = threadIdx.x;
    const int wv = t >> 6, grp = wv >> 2, qh = wv & 3;
    const int lane = t & 63, quad = lane >> 4, r16 = lane & 15;

    u16* sK = sKV[grp][0];
    u16* sV = sKV[grp][1];

    bf16x8 aq[2];
    {
        const size_t qbase = ((((size_t)gb * 4 + qh) * 512) + s16 * 16 + r16) * 64;
#pragma unroll
        for (int kk = 0; kk < 2; ++kk)
            aq[kk] = *(const bf16x8*)(Qa + qbase + kk * 32 + quad * 8);
    }
    const u16* Kg = Ka + (size_t)gb * 4096 * 64;     // [l][d] bf16
    const u16* Vg = Vt + (size_t)gb * 64 * 4096;     // [d][l] f16 (masked)
    const u16* mb = mh + b * 4096 + quad * 4;

    const int tg = t & 255;
    const int r0 = tg >> 3, ks = tg & 7, r1 = r0 + 32;
    const int off0 = (r0 * 64 + ks * 8) ^ ((r0 & 7) << 3);   // XOR-swizzled
    const int off1 = (r1 * 64 + ks * 8) ^ ((r1 & 7) << 3);

    f32x4 o[4], lacc;
#pragma unroll
    for (int i = 0; i < 4; ++i) o[i] = (f32x4){0.f, 0.f, 0.f, 0.f};
    lacc = (f32x4){0.f, 0.f, 0.f, 0.f};

    int4 rk0, rk1, rv0, rv1;
    auto ldtile = [&](int l0) {
        rk0 = *(const int4*)(Kg + (size_t)(l0 + r0) * 64 + ks * 8);
        rk1 = *(const int4*)(Kg + (size_t)(l0 + r1) * 64 + ks * 8);
        rv0 = *(const int4*)(Vg + (size_t)r0 * 4096 + l0 + ks * 8);
        rv1 = *(const int4*)(Vg + (size_t)r1 * 4096 + l0 + ks * 8);
    };
    auto sttile = [&]() {
        *(int4*)(sK + off0) = rk0;
        *(int4*)(sK + off1) = rk1;
        *(int4*)(sV + off0) = rv0;
        *(int4*)(sV + off1) = rv1;
    };

    ldtile(grp * 64);
    for (int i = 0; i < 16; ++i) {
        const int l0 = (i * 4 + grp) * 64;
        sttile();
        __syncthreads();                             // group writes visible
        if (i < 15) ldtile(l0 + 256);                // T14: hide under compute

        f32x4 st[4];
#pragma unroll
        for (int nt = 0; nt < 4; ++nt) st[nt] = (f32x4){0.f, 0.f, 0.f, 0.f};
#pragma unroll
        for (int kk = 0; kk < 2; ++kk)
#pragma unroll
            for (int nt = 0; nt < 4; ++nt) {
                const int kidx = ((nt * 16 + r16) * 64 + kk * 32 + quad * 8) ^ ((r16 & 7) << 3);
                const bf16x8 ka = *(const bf16x8*)(sK + kidx);
                st[nt] = __builtin_amdgcn_mfma_f32_16x16x32_bf16(ka, aq[kk], st[nt], 0, 0, 0);
            }

#pragma unroll
        for (int nt = 0; nt < 4; ++nt) {
            f16x4 pa;
#pragma unroll
            for (int j = 0; j < 4; ++j)
                pa[j] = (_Float16)__builtin_amdgcn_exp2f(st[nt][j]);
            const f16x4 bvm = *(const f16x4*)(mb + l0 + nt * 16);
            lacc = __builtin_amdgcn_mfma_f32_16x16x16f16(pa, bvm, lacc, 0, 0, 0);
#pragma unroll
            for (int dt = 0; dt < 4; ++dt) {
                const int vidx = ((dt * 16 + r16) * 64 + nt * 16 + quad * 4) ^ ((r16 & 7) << 3);
                const f16x4 bv = *(const f16x4*)(sV + vidx);
                o[dt] = __builtin_amdgcn_mfma_f32_16x16x16f16(pa, bv, o[dt], 0, 0, 0);
            }
        }
        __syncthreads();                             // reads done, buffer free
    }

    // ---- block-local combine: groups 1-3 dump partials, group 0 sums ------
    float* fp = (float*)sKV;                         // 16384 floats
    if (grp > 0) {
#pragma unroll
        for (int dt = 0; dt < 4; ++dt)
#pragma unroll
            for (int r = 0; r < 4; ++r)
                fp[(grp - 1) * 4096 + qh * 1024 + (quad * 4 + r) * 64 + dt * 16 + r16] = o[dt][r];
        if (r16 == 0) {
#pragma unroll
            for (int r = 0; r < 4; ++r)
                fp[12288 + ((grp - 1) * 4 + qh) * 16 + quad * 4 + r] = lacc[r];
        }
    }
    __syncthreads();
    if (grp == 0) {
        float Ls[4];
#pragma unroll
        for (int r = 0; r < 4; ++r) Ls[r] = lacc[r];
#pragma unroll
        for (int p = 0; p < 3; ++p) {
#pragma unroll
            for (int dt = 0; dt < 4; ++dt)
#pragma unroll
                for (int r = 0; r < 4; ++r)
                    o[dt][r] += fp[p * 4096 + qh * 1024 + (quad * 4 + r) * 64 + dt * 16 + r16];
#pragma unroll
            for (int r = 0; r < 4; ++r)
                Ls[r] += fp[12288 + (p * 4 + qh) * 16 + quad * 4 + r];
        }
        const size_t obase = ((size_t)b * 512 + s16 * 16) * 1024 + (g * 4 + qh) * 64;
#pragma unroll
        for (int r = 0; r < 4; ++r) {
            const float invL = 1.f / Ls[r];
            const size_t rbase = obase + (size_t)(quad * 4 + r) * 1024;
#pragma unroll
            for (int dt = 0; dt < 4; ++dt)
                attnout[rbase + dt * 16 + r16] = f2bf(o[dt][r] * invL);
        }
    }
}

// ---------------------------------------------------------------------------
extern "C" void kernel_launch(void* const* d_in, const int* in_sizes, int n_in,
                              void* d_out, int out_size, void* d_ws, size_t ws_size,
                              hipStream_t stream) {
    const float* hid  = (const float*)d_in[0];
    const float* enc  = (const float*)d_in[1];
    const int*   mask = (const int*)d_in[2];
    const float* Wq   = (const float*)d_in[3];
    const float* Wk   = (const float*)d_in[4];
    const float* Wv   = (const float*)d_in[5];
    const float* Wo   = (const float*)d_in[6];
    float* out = (float*)d_out;

    char* ws = (char*)d_ws;
    size_t off = 0;
    auto alloc = [&](size_t bytes) -> char* {
        char* p = ws + off;
        off += (bytes + 255) & ~(size_t)255;
        return p;
    };
    u16* Wq_t  = (u16*)alloc((size_t)1024 * 1024 * 2);
    u16* Wkv_t = (u16*)alloc((size_t)512 * 1024 * 2);
    u16* Wo_t  = (u16*)alloc((size_t)1024 * 1024 * 2);
    u16* encb  = (u16*)alloc((size_t)8192 * 1024 * 2);     // 16 MB
    u16* poolb = (u16*)alloc((size_t)1024 * 1024 * 2);     // 2 MB
    u16* Qa    = (u16*)alloc((size_t)1024 * 1024 * 2);
    u16* Ka    = (u16*)alloc((size_t)8 * 4096 * 64 * 2);   // bf16 [l][d]
    u16* Va    = (u16*)alloc((size_t)8 * 4096 * 64 * 2);   // f16  [d][l], masked
    u16* attn  = (u16*)alloc((size_t)1024 * 1024 * 2);
    u16* mh    = (u16*)alloc((size_t)8192 * 2);            // f16 0/1 mask

    prep_all<<<4609, 256, 0, stream>>>(enc, hid, mask, Wq, Wk, Wv, Wo,
                                       encb, poolb, mh, Wq_t, Wkv_t, Wo_t);
    gemm_qkv<<<768, 256, 0, stream>>>(poolb, encb, Wq_t, Wkv_t, mask, Qa, Ka, Va);
    flash_attn<<<256, 1024, 0, stream>>>(Qa, Ka, Va, mh, attn);
    gemm_o_bcast<<<1024, 256, 0, stream>>>(attn, Wo_t, out);
}